// Round 1
// baseline (2020.567 us; speedup 1.0000x reference)
//
#include <hip/hip_runtime.h>

// FirUpsample: fused transposed-conv(3x3, stride-2 up, 256->256) + depthwise 4x4 FIR.
// Composite form: out[n,oc,2a+ry,2b+rx] = sum_ic sum_{j,i in 0..2}
//   x[n,ic,a-1+j,b-1+i] * W_eff[oc,ic,2j+1-ry,2i+1-rx]
// W_eff[ty,tx] = sum_{ky,kx} w[ky,kx] * kf[ty-ky] * kf[tx-kx], kf = {.25,.75,.75,.25}

#define XIC 256
#define XOC 256
#define XH 64
#define XW 64
#define OHW 128

constexpr int OCT  = 16;   // oc per block
constexpr int ICCH = 32;   // ic chunk staged as composite taps in LDS

__device__ __forceinline__ void load_row(const float* __restrict__ xrow,
                                         bool rowok, bool cL, bool cR, int b0,
                                         float r[10]) {
  if (rowok) {
    r[0] = cL ? xrow[b0 - 1] : 0.f;
#pragma unroll
    for (int c = 1; c < 9; ++c) r[c] = xrow[b0 - 1 + c];
    r[9] = cR ? xrow[b0 + 8] : 0.f;
  } else {
#pragma unroll
    for (int c = 0; c < 10; ++c) r[c] = 0.f;
  }
}

__global__ __launch_bounds__(256)
void fir_up_fused(const float* __restrict__ x, const float* __restrict__ w,
                  float* __restrict__ out) {
  const int bid   = blockIdx.x;
  const int stile = bid & 3;          // 4 spatial tiles (32x32 in coarse grid)
  const int oct   = (bid >> 2) & 15;  // 16 oc tiles
  const int n     = (bid >> 6) & 3;   // batch
  const int par   = (bid >> 8) & 3;   // output parity class
  const int ry = par >> 1, rx = par & 1;
  const int a0b = (stile >> 1) * 32;
  const int b0b = (stile & 1) * 32;

  const int tid = threadIdx.x;
  const int ocx = tid & 15;           // lanes 0..15 share spatial window -> x broadcast
  const int sp  = tid >> 4;
  const int spy = sp >> 2, spx = sp & 3;
  const int a0 = a0b + spy * 8;
  const int b0 = b0b + spx * 8;

  __shared__ float Wp[ICCH][OCT][10];  // composite 3x3 taps, +1 pad vs bank conflicts

  // parity coefficient tables: cy[j][ky] = kf[2j+1-ry-ky], cx[i][kx] = kf[2i+1-rx-kx]
  float cy[3][3], cx[3][3];
#pragma unroll
  for (int j = 0; j < 3; ++j) {
#pragma unroll
    for (int kq = 0; kq < 3; ++kq) {
      const int my = 2 * j + 1 - ry - kq;
      cy[j][kq] = (my < 0 || my > 3) ? 0.f : ((my == 1 || my == 2) ? 0.75f : 0.25f);
      const int mx = 2 * j + 1 - rx - kq;
      cx[j][kq] = (mx < 0 || mx > 3) ? 0.f : ((mx == 1 || mx == 2) ? 0.75f : 0.25f);
    }
  }

  const bool cL = (b0 > 0);
  const bool cR = (b0 + 8 < XW);

  float acc[8][8];
#pragma unroll
  for (int i = 0; i < 8; ++i)
#pragma unroll
    for (int j = 0; j < 8; ++j) acc[i][j] = 0.f;

  for (int icc = 0; icc < XIC; icc += ICCH) {
    __syncthreads();  // protect previous chunk's Wp from overwrite
    // build composite taps for this (parity, oc-tile, ic-chunk): 512 pairs / 256 thr
#pragma unroll
    for (int t = 0; t < 2; ++t) {
      const int q    = tid + t * 256;
      const int ic_l = q >> 4;
      const int oc_l = q & 15;
      const float* wp = w + ((size_t)(oct * OCT + oc_l) * XIC + (icc + ic_l)) * 9;
      float wv[9];
#pragma unroll
      for (int u = 0; u < 9; ++u) wv[u] = wp[u];
      float tmp[3][3];  // separable: contract kx first
#pragma unroll
      for (int ky = 0; ky < 3; ++ky)
#pragma unroll
        for (int i = 0; i < 3; ++i)
          tmp[ky][i] = wv[3*ky+0] * cx[i][0] + wv[3*ky+1] * cx[i][1] + wv[3*ky+2] * cx[i][2];
#pragma unroll
      for (int j = 0; j < 3; ++j)
#pragma unroll
        for (int i = 0; i < 3; ++i)
          Wp[ic_l][oc_l][3*j+i] =
              cy[j][0] * tmp[0][i] + cy[j][1] * tmp[1][i] + cy[j][2] * tmp[2][i];
    }
    __syncthreads();

    for (int il = 0; il < ICCH; ++il) {
      const int ic = icc + il;
      const float* xpl = x + ((size_t)(n * XIC + ic) * XH) * XW;
      float wv[9];
#pragma unroll
      for (int u = 0; u < 9; ++u) wv[u] = Wp[il][ocx][u];

      float rows[3][10];  // rolling 3-row window, all indices compile-time after unroll
      load_row(xpl + (a0 - 1) * XW, a0 >= 1, cL, cR, b0, rows[0]);
      load_row(xpl + a0 * XW, true, cL, cR, b0, rows[1]);
#pragma unroll
      for (int dy = 0; dy < 8; ++dy) {
        const int iy = a0 + dy + 1;
        load_row(xpl + iy * XW, iy < XH, cL, cR, b0, rows[(dy + 2) % 3]);
#pragma unroll
        for (int dx = 0; dx < 8; ++dx) {
          float s = acc[dy][dx];
          s += wv[0] * rows[dy % 3][dx]     + wv[1] * rows[dy % 3][dx + 1]
             + wv[2] * rows[dy % 3][dx + 2];
          s += wv[3] * rows[(dy + 1) % 3][dx]     + wv[4] * rows[(dy + 1) % 3][dx + 1]
             + wv[5] * rows[(dy + 1) % 3][dx + 2];
          s += wv[6] * rows[(dy + 2) % 3][dx]     + wv[7] * rows[(dy + 2) % 3][dx + 1]
             + wv[8] * rows[(dy + 2) % 3][dx + 2];
          acc[dy][dx] = s;
        }
      }
    }
  }

  const int oc = oct * OCT + ocx;
  float* op = out + ((size_t)n * XOC + oc) * OHW * OHW;
#pragma unroll
  for (int dy = 0; dy < 8; ++dy) {
    const int oy = 2 * (a0 + dy) + ry;
#pragma unroll
    for (int dx = 0; dx < 8; ++dx) {
      const int ox = 2 * (b0 + dx) + rx;
      op[oy * OHW + ox] = acc[dy][dx];
    }
  }
}

extern "C" void kernel_launch(void* const* d_in, const int* in_sizes, int n_in,
                              void* d_out, int out_size, void* d_ws, size_t ws_size,
                              hipStream_t stream) {
  (void)in_sizes; (void)n_in; (void)out_size; (void)d_ws; (void)ws_size;
  const float* x = (const float*)d_in[0];
  const float* w = (const float*)d_in[1];
  float* out = (float*)d_out;
  // grid = parity(4) * n(4) * oc-tiles(16) * spatial-tiles(4) = 1024 blocks
  hipLaunchKernelGGL(fir_up_fused, dim3(1024), dim3(256), 0, stream, x, w, out);
}